// Round 1
// baseline (1071.421 us; speedup 1.0000x reference)
//
#include <hip/hip_runtime.h>

#define KK 8192
#define DD 64
#define NN 16384
#define TOKW 8          // tokens per wave
#define DECAYF 0.99f
#define EPSF 1e-5f
#define BATCHF 32.0f

// ---------------- zero workspace (sums + counts) ----------------
__global__ __launch_bounds__(256) void zero_ws_kernel(float4* __restrict__ p, int n4) {
  int i = blockIdx.x * 256 + threadIdx.x;
  if (i < n4) p[i] = make_float4(0.f, 0.f, 0.f, 0.f);
}

// ---------------- per-code squared norms ----------------
__global__ __launch_bounds__(256) void c2_kernel(const float* __restrict__ cb,
                                                 float* __restrict__ c2) {
  int k = blockIdx.x * 256 + threadIdx.x;   // grid sized exactly K
  const float4* r = (const float4*)(cb + (size_t)k * DD);
  float s = 0.f;
  #pragma unroll
  for (int i = 0; i < DD / 4; ++i) {
    float4 v = r[i];
    s = fmaf(v.x, v.x, s);
    s = fmaf(v.y, v.y, s);
    s = fmaf(v.z, v.z, s);
    s = fmaf(v.w, v.w, s);
  }
  c2[k] = s;
}

// ---------------- main: exact fp32 argmin + fused side-products ----------------
// Wave-level layout: wave owns TOKW tokens (x rows wave-uniform -> scalar loads),
// lane owns code (tile*64 + lane). Running per-lane best, then 64-lane butterfly
// argmin reduce with lowest-index tie-break (matches jnp.argmin first-min).
__global__ __launch_bounds__(256) void argmin_kernel(
    const float* __restrict__ x, const float* __restrict__ cb,
    const float* __restrict__ c2, int* __restrict__ idx_out,
    float* __restrict__ quant, float* __restrict__ counts,
    float* __restrict__ sums) {
  const int lane = threadIdx.x & 63;
  const int wave = __builtin_amdgcn_readfirstlane(threadIdx.x >> 6);
  const int tok0 = (blockIdx.x * 4 + wave) * TOKW;

  float best[TOKW];
  int bidx[TOKW];
  #pragma unroll
  for (int t = 0; t < TOKW; ++t) { best[t] = 3.4e38f; bidx[t] = 0; }

  const float4* x4 = (const float4*)(x + (size_t)tok0 * DD);  // wave-uniform base
  const float4* cb4 = (const float4*)cb;

  for (int ct = 0; ct < KK / 64; ++ct) {
    const int code = ct * 64 + lane;
    float dot[TOKW];
    #pragma unroll
    for (int t = 0; t < TOKW; ++t) dot[t] = 0.f;

    #pragma unroll
    for (int db = 0; db < DD / 4; ++db) {
      float4 cv = cb4[(size_t)code * (DD / 4) + db];   // per-lane codebook stream (L1/L2)
      #pragma unroll
      for (int t = 0; t < TOKW; ++t) {
        float4 xv = x4[t * (DD / 4) + db];             // wave-uniform -> SGPR operand
        dot[t] = fmaf(xv.x, cv.x, dot[t]);
        dot[t] = fmaf(xv.y, cv.y, dot[t]);
        dot[t] = fmaf(xv.z, cv.z, dot[t]);
        dot[t] = fmaf(xv.w, cv.w, dot[t]);
      }
    }
    const float cc = c2[code];
    #pragma unroll
    for (int t = 0; t < TOKW; ++t) {
      float sc = fmaf(-2.f, dot[t], cc);   // ||x||^2 dropped: argmin-invariant
      if (sc < best[t]) { best[t] = sc; bidx[t] = code; }  // strict < keeps lowest code
    }
  }

  // 64-lane butterfly argmin with index tie-break
  #pragma unroll
  for (int off = 32; off; off >>= 1) {
    #pragma unroll
    for (int t = 0; t < TOKW; ++t) {
      float os = __shfl_xor(best[t], off, 64);
      int oi = __shfl_xor(bidx[t], off, 64);
      if (os < best[t] || (os == best[t] && oi < bidx[t])) {
        best[t] = os; bidx[t] = oi;
      }
    }
  }

  // idx + counts histogram (one lane per token)
  #pragma unroll
  for (int t = 0; t < TOKW; ++t) {
    if (lane == t) {
      idx_out[tok0 + t] = bidx[t];
      atomicAdd(&counts[bidx[t]], 1.0f);   // exact integer adds in fp32
    }
  }

  // quantized rows + scatter-add of x into per-code sums (coalesced: lane = d)
  #pragma unroll
  for (int t = 0; t < TOKW; ++t) {
    const int bu = __builtin_amdgcn_readfirstlane(bidx[t]);  // uniform post-reduction
    const size_t n = (size_t)(tok0 + t);
    const float xv = x[n * DD + lane];
    quant[n * DD + lane] = cb[(size_t)bu * DD + lane];
    atomicAdd(&sums[(size_t)bu * DD + lane], xv);
  }
}

// ---------------- one-hot fill: single pass, write-only 536 MB ----------------
__global__ __launch_bounds__(256) void fill_kernel(const int* __restrict__ idx,
                                                   float4* __restrict__ d4) {
  const size_t stride = (size_t)gridDim.x * 256;
  const size_t total = (size_t)NN * (KK / 4);
  for (size_t g = (size_t)blockIdx.x * 256 + threadIdx.x; g < total; g += stride) {
    const int n = (int)(g >> 11);          // 2048 float4 per row
    const int k0 = ((int)g & 2047) << 2;
    const int bi = idx[n];                 // broadcast within wave, L1-hit
    float4 v;
    v.x = (k0 == bi) ? 1.f : 0.f;
    v.y = (k0 + 1 == bi) ? 1.f : 0.f;
    v.z = (k0 + 2 == bi) ? 1.f : 0.f;
    v.w = (k0 + 3 == bi) ? 1.f : 0.f;
    d4[g] = v;
  }
}

// ---------------- EMA finalize ----------------
__global__ __launch_bounds__(256) void finalize_kernel(
    const float* __restrict__ ema_count, const float* __restrict__ ema_weight,
    const float* __restrict__ counts, const float* __restrict__ sums,
    float* __restrict__ out_count, float* __restrict__ out_weight,
    float* __restrict__ out_cb) {
  const int e4 = blockIdx.x * 256 + threadIdx.x;  // grid sized exactly K*D/4
  const int k = e4 >> 4;                          // 16 float4 per code row

  float nc = ema_count[k] * DECAYF + counts[k] * (1.f - DECAYF);
  nc = (nc + EPSF) / (BATCHF + (float)KK * EPSF) * BATCHF;

  const float4 ew = ((const float4*)ema_weight)[e4];
  const float4 s = ((const float4*)sums)[e4];
  float4 nw;
  nw.x = ew.x * DECAYF + s.x * (1.f - DECAYF);
  nw.y = ew.y * DECAYF + s.y * (1.f - DECAYF);
  nw.z = ew.z * DECAYF + s.z * (1.f - DECAYF);
  nw.w = ew.w * DECAYF + s.w * (1.f - DECAYF);
  ((float4*)out_weight)[e4] = nw;

  float4 ncb;
  ncb.x = nw.x / nc;
  ncb.y = nw.y / nc;
  ncb.z = nw.z / nc;
  ncb.w = nw.w / nc;
  ((float4*)out_cb)[e4] = ncb;

  if ((e4 & 15) == 0) out_count[k] = nc;
}

extern "C" void kernel_launch(void* const* d_in, const int* in_sizes, int n_in,
                              void* d_out, int out_size, void* d_ws, size_t ws_size,
                              hipStream_t stream) {
  const float* x = (const float*)d_in[0];           // [16384, 64]
  const float* cb = (const float*)d_in[1];          // [8192, 64]
  const float* ema_count = (const float*)d_in[2];   // [8192]
  const float* ema_weight = (const float*)d_in[3];  // [8192, 64]

  float* out = (float*)d_out;
  float* disc = out;                                   // N*K
  float* quant = disc + (size_t)NN * KK;               // N*D
  float* out_count = quant + (size_t)NN * DD;          // K
  float* out_weight = out_count + KK;                  // K*D
  float* out_cb = out_weight + (size_t)KK * DD;        // K*D

  float* ws = (float*)d_ws;
  float* sums = ws;                                    // K*D floats
  float* counts = sums + (size_t)KK * DD;              // K floats
  float* c2 = counts + KK;                             // K floats
  int* idxb = (int*)(c2 + KK);                         // N ints

  // sums + counts = 532480 floats = 133120 float4 -> 520 blocks exactly
  zero_ws_kernel<<<520, 256, 0, stream>>>((float4*)ws, (KK * DD + KK) / 4);
  c2_kernel<<<KK / 256, 256, 0, stream>>>(cb, c2);
  argmin_kernel<<<512, 256, 0, stream>>>(x, cb, c2, idxb, quant, counts, sums);
  fill_kernel<<<2048, 256, 0, stream>>>(idxb, (float4*)disc);
  finalize_kernel<<<KK * DD / 4 / 256, 256, 0, stream>>>(
      ema_count, ema_weight, counts, sums, out_count, out_weight, out_cb);
}

// Round 2
// 1016.335 us; speedup vs baseline: 1.0542x; 1.0542x over previous
//
#include <hip/hip_runtime.h>

#define KK 8192
#define DD 64
#define NN 16384
#define DECAYF 0.99f
#define EPSF 1e-5f
#define BATCHF 32.0f
#define CSPLIT 16
#define CODES_PER_BLK (KK / CSPLIT)   // 512
#define MARGIN 3.0f
#define LISTCAP 262144u

using short8  = __attribute__((ext_vector_type(8))) short;
using floatx4 = __attribute__((ext_vector_type(4))) float;

// ---- helpers ----
__device__ __forceinline__ unsigned short f2bf(float f) {  // RNE bf16
  unsigned u = __float_as_uint(f);
  return (unsigned short)((u + 0x7FFFu + ((u >> 16) & 1u)) >> 16);
}
__device__ __forceinline__ unsigned ford(float f) {        // order-preserving f32->u32
  unsigned u = __float_as_uint(f);
  return (u & 0x80000000u) ? ~u : (u | 0x80000000u);
}
__device__ __forceinline__ float funord(unsigned u) {      // inverse
  unsigned b = (u & 0x80000000u) ? (u ^ 0x80000000u) : ~u;
  return __uint_as_float(b);
}

// ---- init workspace: zero sums+counts, init minc / best / list counter ----
__global__ __launch_bounds__(256) void init_kernel(float4* __restrict__ sums4,
                                                   unsigned* __restrict__ minc,
                                                   unsigned long long* __restrict__ best,
                                                   unsigned* __restrict__ cnt) {
  int i = blockIdx.x * 256 + threadIdx.x;   // grid 520 -> 133120 threads
  if (i < (KK * DD + KK) / 4) sums4[i] = make_float4(0.f, 0.f, 0.f, 0.f);
  if (i < NN) { minc[i] = 0xFFFFFFFFu; best[i] = ~0ULL; }
  if (i == 0) *cnt = 0u;
}

// ---- fp32 -> bf16 conversion (x and codebook) ----
__global__ __launch_bounds__(256) void conv_kernel(const float4* __restrict__ src,
                                                   uint2* __restrict__ dst, int n4) {
  int i = blockIdx.x * 256 + threadIdx.x;
  if (i >= n4) return;
  float4 v = src[i];
  uint2 o;
  o.x = (unsigned)f2bf(v.x) | ((unsigned)f2bf(v.y) << 16);
  o.y = (unsigned)f2bf(v.z) | ((unsigned)f2bf(v.w) << 16);
  dst[i] = o;
}

// ---- exact fp32 per-code squared norms ----
__global__ __launch_bounds__(256) void c2_kernel(const float* __restrict__ cb,
                                                 float* __restrict__ c2) {
  int k = blockIdx.x * 256 + threadIdx.x;   // grid KK/256
  const float4* r = (const float4*)(cb + (size_t)k * DD);
  float s = 0.f;
  #pragma unroll
  for (int i = 0; i < DD / 4; ++i) {
    float4 v = r[i];
    s = fmaf(v.x, v.x, s); s = fmaf(v.y, v.y, s);
    s = fmaf(v.z, v.z, s); s = fmaf(v.w, v.w, s);
  }
  c2[k] = s;
}

// ---- pass 1: bf16 MFMA coarse min per token ----
// wave = 64 tokens (4 subtiles of 16), block = 4 waves = 256 tokens.
// grid = 64 token-blocks x CSPLIT code-splits. No LDS; A-frags in registers,
// B-frags streamed from L2-resident bf16 codebook (1 MB).
__global__ __launch_bounds__(256) void pass1_kernel(const unsigned short* __restrict__ xb,
                                                    const unsigned short* __restrict__ cbb,
                                                    const float* __restrict__ c2,
                                                    unsigned* __restrict__ minc) {
  const int lane = threadIdx.x & 63;
  const int wave = threadIdx.x >> 6;
  const int tokbase = (blockIdx.x / CSPLIT) * 256 + wave * 64;
  const int code0 = (blockIdx.x % CSPLIT) * CODES_PER_BLK;
  const int q = lane >> 4, col = lane & 15;

  short8 a[4][2];
  #pragma unroll
  for (int s = 0; s < 4; ++s)
    #pragma unroll
    for (int kk = 0; kk < 2; ++kk)
      a[s][kk] = *(const short8*)(xb + (size_t)(tokbase + s * 16 + col) * DD + kk * 32 + q * 8);

  float mn[4][4];
  #pragma unroll
  for (int s = 0; s < 4; ++s)
    #pragma unroll
    for (int r = 0; r < 4; ++r) mn[s][r] = 3.4e38f;

  for (int ct = 0; ct < CODES_PER_BLK / 16; ++ct) {
    const int code = code0 + ct * 16 + col;
    short8 b0 = *(const short8*)(cbb + (size_t)code * DD + q * 8);
    short8 b1 = *(const short8*)(cbb + (size_t)code * DD + 32 + q * 8);
    const float c2v = c2[code];
    #pragma unroll
    for (int s = 0; s < 4; ++s) {
      floatx4 acc = {0.f, 0.f, 0.f, 0.f};
      acc = __builtin_amdgcn_mfma_f32_16x16x32_bf16(a[s][0], b0, acc, 0, 0, 0);
      acc = __builtin_amdgcn_mfma_f32_16x16x32_bf16(a[s][1], b1, acc, 0, 0, 0);
      #pragma unroll
      for (int r = 0; r < 4; ++r)
        mn[s][r] = fminf(mn[s][r], fmaf(-2.f, acc[r], c2v));
    }
  }

  #pragma unroll
  for (int off = 1; off < 16; off <<= 1)
    #pragma unroll
    for (int s = 0; s < 4; ++s)
      #pragma unroll
      for (int r = 0; r < 4; ++r)
        mn[s][r] = fminf(mn[s][r], __shfl_xor(mn[s][r], off, 64));

  if (col == 0) {
    #pragma unroll
    for (int s = 0; s < 4; ++s)
      #pragma unroll
      for (int r = 0; r < 4; ++r)
        atomicMin(&minc[tokbase + s * 16 + q * 4 + r], ford(mn[s][r]));
  }
}

// ---- pass 2: re-run MFMA, flag candidates within coarse_min + MARGIN ----
__global__ __launch_bounds__(256) void pass2_kernel(const unsigned short* __restrict__ xb,
                                                    const unsigned short* __restrict__ cbb,
                                                    const float* __restrict__ c2,
                                                    const unsigned* __restrict__ minc,
                                                    unsigned* __restrict__ cnt,
                                                    unsigned* __restrict__ list) {
  const int lane = threadIdx.x & 63;
  const int wave = threadIdx.x >> 6;
  const int tokbase = (blockIdx.x / CSPLIT) * 256 + wave * 64;
  const int code0 = (blockIdx.x % CSPLIT) * CODES_PER_BLK;
  const int q = lane >> 4, col = lane & 15;

  short8 a[4][2];
  #pragma unroll
  for (int s = 0; s < 4; ++s)
    #pragma unroll
    for (int kk = 0; kk < 2; ++kk)
      a[s][kk] = *(const short8*)(xb + (size_t)(tokbase + s * 16 + col) * DD + kk * 32 + q * 8);

  float th[4][4];
  #pragma unroll
  for (int s = 0; s < 4; ++s)
    #pragma unroll
    for (int r = 0; r < 4; ++r)
      th[s][r] = funord(minc[tokbase + s * 16 + q * 4 + r]) + MARGIN;

  for (int ct = 0; ct < CODES_PER_BLK / 16; ++ct) {
    const int code = code0 + ct * 16 + col;
    short8 b0 = *(const short8*)(cbb + (size_t)code * DD + q * 8);
    short8 b1 = *(const short8*)(cbb + (size_t)code * DD + 32 + q * 8);
    const float c2v = c2[code];
    #pragma unroll
    for (int s = 0; s < 4; ++s) {
      floatx4 acc = {0.f, 0.f, 0.f, 0.f};
      acc = __builtin_amdgcn_mfma_f32_16x16x32_bf16(a[s][0], b0, acc, 0, 0, 0);
      acc = __builtin_amdgcn_mfma_f32_16x16x32_bf16(a[s][1], b1, acc, 0, 0, 0);
      #pragma unroll
      for (int r = 0; r < 4; ++r) {
        float sc = fmaf(-2.f, acc[r], c2v);
        if (sc < th[s][r]) {   // rare
          unsigned e = ((unsigned)(tokbase + s * 16 + q * 4 + r) << 16) | (unsigned)code;
          unsigned p = atomicAdd(cnt, 1u);
          if (p < LISTCAP) list[p] = e;
        }
      }
    }
  }
}

// ---- exact fp32 refinement of candidates; (score,code) packed u64 atomicMin ----
__global__ __launch_bounds__(256) void refine_kernel(const unsigned* __restrict__ cnt,
                                                     const unsigned* __restrict__ list,
                                                     const float* __restrict__ x,
                                                     const float* __restrict__ cb,
                                                     const float* __restrict__ c2,
                                                     unsigned long long* __restrict__ best) {
  unsigned i = blockIdx.x * 256 + threadIdx.x;   // grid LISTCAP/256
  unsigned n = *cnt; if (n > LISTCAP) n = LISTCAP;
  if (i >= n) return;
  unsigned e = list[i];
  int tok = (int)(e >> 16), code = (int)(e & 0xFFFFu);
  const float4* xr = (const float4*)(x + (size_t)tok * DD);
  const float4* cr = (const float4*)(cb + (size_t)code * DD);
  float d = 0.f;
  #pragma unroll
  for (int j = 0; j < DD / 4; ++j) {
    float4 av = xr[j], bv = cr[j];
    d = fmaf(av.x, bv.x, d); d = fmaf(av.y, bv.y, d);
    d = fmaf(av.z, bv.z, d); d = fmaf(av.w, bv.w, d);
  }
  float sc = fmaf(-2.f, d, c2[code]);
  unsigned long long key = ((unsigned long long)ford(sc) << 32) | (unsigned long long)code;
  atomicMin(&best[tok], key);
}

// ---- per-token finalize: quantized rows, counts, per-code x sums ----
__global__ __launch_bounds__(256) void tokfin_kernel(const unsigned long long* __restrict__ best,
                                                     const float* __restrict__ x,
                                                     const float* __restrict__ cb,
                                                     float* __restrict__ quant,
                                                     float* __restrict__ counts,
                                                     float* __restrict__ sums) {
  const int n = blockIdx.x * 4 + (threadIdx.x >> 6);   // grid 4096
  const int d = threadIdx.x & 63;
  const unsigned code = (unsigned)(best[n] & 0xFFFFFFFFULL);
  quant[(size_t)n * DD + d] = cb[(size_t)code * DD + d];
  atomicAdd(&sums[(size_t)code * DD + d], x[(size_t)n * DD + d]);
  if (d == 0) atomicAdd(&counts[code], 1.0f);
}

// ---- scatter the ones into the (memset-zeroed) one-hot matrix ----
__global__ __launch_bounds__(256) void scatter_kernel(const unsigned long long* __restrict__ best,
                                                      float* __restrict__ disc) {
  const int n = blockIdx.x * 256 + threadIdx.x;        // grid 64
  const unsigned code = (unsigned)(best[n] & 0xFFFFFFFFULL);
  disc[(size_t)n * KK + code] = 1.0f;
}

// ---- EMA finalize ----
__global__ __launch_bounds__(256) void finalize_kernel(
    const float* __restrict__ ema_count, const float* __restrict__ ema_weight,
    const float* __restrict__ counts, const float* __restrict__ sums,
    float* __restrict__ out_count, float* __restrict__ out_weight,
    float* __restrict__ out_cb) {
  const int e4 = blockIdx.x * 256 + threadIdx.x;  // grid KK*DD/4/256
  const int k = e4 >> 4;
  float nc = ema_count[k] * DECAYF + counts[k] * (1.f - DECAYF);
  nc = (nc + EPSF) / (BATCHF + (float)KK * EPSF) * BATCHF;
  const float4 ew = ((const float4*)ema_weight)[e4];
  const float4 s  = ((const float4*)sums)[e4];
  float4 nw;
  nw.x = ew.x * DECAYF + s.x * (1.f - DECAYF);
  nw.y = ew.y * DECAYF + s.y * (1.f - DECAYF);
  nw.z = ew.z * DECAYF + s.z * (1.f - DECAYF);
  nw.w = ew.w * DECAYF + s.w * (1.f - DECAYF);
  ((float4*)out_weight)[e4] = nw;
  float4 ncb = make_float4(nw.x / nc, nw.y / nc, nw.z / nc, nw.w / nc);
  ((float4*)out_cb)[e4] = ncb;
  if ((e4 & 15) == 0) out_count[k] = nc;
}

extern "C" void kernel_launch(void* const* d_in, const int* in_sizes, int n_in,
                              void* d_out, int out_size, void* d_ws, size_t ws_size,
                              hipStream_t stream) {
  const float* x  = (const float*)d_in[0];           // [16384, 64]
  const float* cb = (const float*)d_in[1];           // [8192, 64]
  const float* ema_count  = (const float*)d_in[2];   // [8192]
  const float* ema_weight = (const float*)d_in[3];   // [8192, 64]

  float* out        = (float*)d_out;
  float* disc       = out;                            // N*K
  float* quant      = disc + (size_t)NN * KK;         // N*D
  float* out_count  = quant + (size_t)NN * DD;        // K
  float* out_weight = out_count + KK;                 // K*D
  float* out_cb     = out_weight + (size_t)KK * DD;   // K*D

  // workspace layout (float offsets; all 16B-aligned blocks)
  float* ws = (float*)d_ws;
  float*    sums   = ws;                                        // 524288 f
  float*    counts = sums + (size_t)KK * DD;                    // 8192 f
  float*    c2     = counts + KK;                               // 8192 f
  unsigned* minc   = (unsigned*)(c2 + KK);                      // 16384 u32
  unsigned long long* best = (unsigned long long*)(minc + NN);  // 16384 u64
  unsigned* cnt    = (unsigned*)(best + NN);                    // 1 u32 (+15 pad)
  unsigned* list   = cnt + 16;                                  // 262144 u32
  unsigned short* xb  = (unsigned short*)(list + LISTCAP);      // 1M bf16
  unsigned short* cbb = xb + (size_t)NN * DD;                   // 512K bf16

  // zero the one-hot block (driver memset ~ full write BW)
  hipMemsetAsync(disc, 0, (size_t)NN * KK * sizeof(float), stream);

  init_kernel<<<520, 256, 0, stream>>>((float4*)sums, minc, best, cnt);
  conv_kernel<<<NN * DD / 4 / 256, 256, 0, stream>>>((const float4*)x, (uint2*)xb, NN * DD / 4);
  conv_kernel<<<KK * DD / 4 / 256, 256, 0, stream>>>((const float4*)cb, (uint2*)cbb, KK * DD / 4);
  c2_kernel<<<KK / 256, 256, 0, stream>>>(cb, c2);
  pass1_kernel<<<(NN / 256) * CSPLIT, 256, 0, stream>>>(xb, cbb, c2, minc);
  pass2_kernel<<<(NN / 256) * CSPLIT, 256, 0, stream>>>(xb, cbb, c2, minc, cnt, list);
  refine_kernel<<<LISTCAP / 256, 256, 0, stream>>>(cnt, list, x, cb, c2, best);
  tokfin_kernel<<<NN / 4, 256, 0, stream>>>(best, x, cb, quant, counts, sums);
  scatter_kernel<<<NN / 256, 256, 0, stream>>>(best, disc);
  finalize_kernel<<<KK * DD / 4 / 256, 256, 0, stream>>>(
      ema_count, ema_weight, counts, sums, out_count, out_weight, out_cb);
}

// Round 3
// 615.547 us; speedup vs baseline: 1.7406x; 1.6511x over previous
//
#include <hip/hip_runtime.h>

#define KK 8192
#define DD 64
#define NN 16384
#define DECAYF 0.99f
#define EPSF 1e-5f
#define BATCHF 32.0f
#define CSPLIT 32
#define CODES_PER_BLK (KK / CSPLIT)       // 256 codes -> 32 KB bf16 LDS tile
#define NCT (CODES_PER_BLK / 16)          // 16 MFMA code-tiles per block
#define TOKS_PER_WAVE 128                 // 8 subtiles of 16
#define NSUB 8
#define MARGIN_HALF 1.5f                  // half-score margin (full-score 3.0)
#define LISTCAP 262144u
#define LBUFCAP 1024u

using short8  = __attribute__((ext_vector_type(8))) short;
using floatx4 = __attribute__((ext_vector_type(4))) float;

// ---- helpers ----
__device__ __forceinline__ unsigned short f2bf(float f) {  // RNE bf16
  unsigned u = __float_as_uint(f);
  return (unsigned short)((u + 0x7FFFu + ((u >> 16) & 1u)) >> 16);
}
__device__ __forceinline__ unsigned ford(float f) {        // order-preserving f32->u32
  unsigned u = __float_as_uint(f);
  return (u & 0x80000000u) ? ~u : (u | 0x80000000u);
}
__device__ __forceinline__ float funord(unsigned u) {
  unsigned b = (u & 0x80000000u) ? (u ^ 0x80000000u) : ~u;
  return __uint_as_float(b);
}

// ---- init workspace ----
__global__ __launch_bounds__(256) void init_kernel(float4* __restrict__ sums4,
                                                   unsigned* __restrict__ minc,
                                                   unsigned long long* __restrict__ best,
                                                   unsigned* __restrict__ cnt) {
  int i = blockIdx.x * 256 + threadIdx.x;   // grid 520
  if (i < (KK * DD + KK) / 4) sums4[i] = make_float4(0.f, 0.f, 0.f, 0.f);
  if (i < NN) { minc[i] = 0xFFFFFFFFu; best[i] = ~0ULL; }
  if (i == 0) *cnt = 0u;
}

// ---- fp32 -> bf16 ----
__global__ __launch_bounds__(256) void conv_kernel(const float4* __restrict__ src,
                                                   uint2* __restrict__ dst, int n4) {
  int i = blockIdx.x * 256 + threadIdx.x;
  if (i >= n4) return;
  float4 v = src[i];
  uint2 o;
  o.x = (unsigned)f2bf(v.x) | ((unsigned)f2bf(v.y) << 16);
  o.y = (unsigned)f2bf(v.z) | ((unsigned)f2bf(v.w) << 16);
  dst[i] = o;
}

// ---- exact fp32 per-code squared norms ----
__global__ __launch_bounds__(256) void c2_kernel(const float* __restrict__ cb,
                                                 float* __restrict__ c2) {
  int k = blockIdx.x * 256 + threadIdx.x;
  const float4* r = (const float4*)(cb + (size_t)k * DD);
  float s = 0.f;
  #pragma unroll
  for (int i = 0; i < DD / 4; ++i) {
    float4 v = r[i];
    s = fmaf(v.x, v.x, s); s = fmaf(v.y, v.y, s);
    s = fmaf(v.z, v.z, s); s = fmaf(v.w, v.w, s);
  }
  c2[k] = s;
}

// ---- shared LDS staging: 256-code bf16 slice, XOR-swizzled 16B chunks ----
// tile[r*8 + c] holds global chunk (c ^ (r&7)) of row (code0+r): hot-loop
// ds_read_b128 then hits 8 lanes/bank-group (the b128 floor) instead of 16.
__device__ __forceinline__ void stage_tile(const float4* __restrict__ cbb4,
                                           const float* __restrict__ c2,
                                           int code0, float4* tile, float* c2s) {
  const int tid = threadIdx.x;
  #pragma unroll
  for (int it = 0; it < 8; ++it) {
    int C = it * 256 + tid;          // linear 16B chunk 0..2047
    int r = C >> 3, c = C & 7;
    tile[C] = cbb4[(size_t)(code0 + r) * 8 + (c ^ (r & 7))];
  }
  c2s[tid] = c2[code0 + tid];        // 256 threads = 256 codes
}

// ---- pass 1: bf16 MFMA coarse half-score min per token ----
// wave = 128 tokens (8 subtiles), block = 4 waves = 512 tokens.
// grid = 32 token-blocks x CSPLIT splits = 1024 blocks.
__global__ __launch_bounds__(256, 2) void pass1_kernel(const unsigned short* __restrict__ xb,
                                                       const float4* __restrict__ cbb4,
                                                       const float* __restrict__ c2,
                                                       unsigned* __restrict__ minc) {
  __shared__ float4 tile[CODES_PER_BLK * 8];
  __shared__ float c2s[CODES_PER_BLK];
  const int lane = threadIdx.x & 63;
  const int wave = threadIdx.x >> 6;
  const int col = lane & 15, q = lane >> 4;
  const int tokbase = (blockIdx.x / CSPLIT) * 512 + wave * TOKS_PER_WAVE;
  const int code0 = (blockIdx.x % CSPLIT) * CODES_PER_BLK;

  stage_tile(cbb4, c2, code0, tile, c2s);

  short8 a[NSUB][2];
  #pragma unroll
  for (int s = 0; s < NSUB; ++s)
    #pragma unroll
    for (int kk = 0; kk < 2; ++kk)
      a[s][kk] = *(const short8*)(xb + (size_t)(tokbase + s * 16 + col) * DD + kk * 32 + q * 8);

  float mn[NSUB][4];
  #pragma unroll
  for (int s = 0; s < NSUB; ++s)
    #pragma unroll
    for (int r = 0; r < 4; ++r) mn[s][r] = 3.4e38f;

  __syncthreads();

  for (int ct = 0; ct < NCT; ++ct) {
    const int row = ct * 16 + col;
    const int rb = row * 8, rx = row & 7;
    short8 b0 = *(const short8*)&tile[rb + (q ^ rx)];
    short8 b1 = *(const short8*)&tile[rb + ((q + 4) ^ rx)];
    const float h = 0.5f * c2s[row];
    #pragma unroll
    for (int s = 0; s < NSUB; ++s) {
      floatx4 acc = {0.f, 0.f, 0.f, 0.f};
      acc = __builtin_amdgcn_mfma_f32_16x16x32_bf16(a[s][0], b0, acc, 0, 0, 0);
      acc = __builtin_amdgcn_mfma_f32_16x16x32_bf16(a[s][1], b1, acc, 0, 0, 0);
      #pragma unroll
      for (int r = 0; r < 4; ++r)
        mn[s][r] = fminf(mn[s][r], h - acc[r]);   // half-score = 0.5*c2 - dot
    }
  }

  #pragma unroll
  for (int off = 1; off < 16; off <<= 1)
    #pragma unroll
    for (int s = 0; s < NSUB; ++s)
      #pragma unroll
      for (int r = 0; r < 4; ++r)
        mn[s][r] = fminf(mn[s][r], __shfl_xor(mn[s][r], off, 64));

  if (col == 0) {
    #pragma unroll
    for (int s = 0; s < NSUB; ++s)
      #pragma unroll
      for (int r = 0; r < 4; ++r)
        atomicMin(&minc[tokbase + s * 16 + q * 4 + r], ford(mn[s][r]));
  }
}

// ---- pass 2: rescan, flag candidates < global_half_min + MARGIN_HALF ----
// Candidates buffered in LDS; ONE global atomicAdd per block.
__global__ __launch_bounds__(256, 2) void pass2_kernel(const unsigned short* __restrict__ xb,
                                                       const float4* __restrict__ cbb4,
                                                       const float* __restrict__ c2,
                                                       const unsigned* __restrict__ minc,
                                                       unsigned* __restrict__ cnt,
                                                       unsigned* __restrict__ list) {
  __shared__ float4 tile[CODES_PER_BLK * 8];
  __shared__ float c2s[CODES_PER_BLK];
  __shared__ unsigned lbuf[LBUFCAP];
  __shared__ unsigned lcnt, gbase;
  const int lane = threadIdx.x & 63;
  const int wave = threadIdx.x >> 6;
  const int col = lane & 15, q = lane >> 4;
  const int tokbase = (blockIdx.x / CSPLIT) * 512 + wave * TOKS_PER_WAVE;
  const int code0 = (blockIdx.x % CSPLIT) * CODES_PER_BLK;

  if (threadIdx.x == 0) lcnt = 0u;
  stage_tile(cbb4, c2, code0, tile, c2s);

  short8 a[NSUB][2];
  #pragma unroll
  for (int s = 0; s < NSUB; ++s)
    #pragma unroll
    for (int kk = 0; kk < 2; ++kk)
      a[s][kk] = *(const short8*)(xb + (size_t)(tokbase + s * 16 + col) * DD + kk * 32 + q * 8);

  float th[NSUB][4];
  #pragma unroll
  for (int s = 0; s < NSUB; ++s)
    #pragma unroll
    for (int r = 0; r < 4; ++r)
      th[s][r] = funord(minc[tokbase + s * 16 + q * 4 + r]) + MARGIN_HALF;

  __syncthreads();

  for (int ct = 0; ct < NCT; ++ct) {
    const int row = ct * 16 + col;
    const int rb = row * 8, rx = row & 7;
    short8 b0 = *(const short8*)&tile[rb + (q ^ rx)];
    short8 b1 = *(const short8*)&tile[rb + ((q + 4) ^ rx)];
    const float h = 0.5f * c2s[row];
    const int code = code0 + row;
    #pragma unroll
    for (int s = 0; s < NSUB; ++s) {
      floatx4 acc = {0.f, 0.f, 0.f, 0.f};
      acc = __builtin_amdgcn_mfma_f32_16x16x32_bf16(a[s][0], b0, acc, 0, 0, 0);
      acc = __builtin_amdgcn_mfma_f32_16x16x32_bf16(a[s][1], b1, acc, 0, 0, 0);
      #pragma unroll
      for (int r = 0; r < 4; ++r) {
        if (h - acc[r] < th[s][r]) {   // rare
          unsigned tok = (unsigned)(tokbase + s * 16 + q * 4 + r);
          unsigned p = atomicAdd(&lcnt, 1u);
          if (p < LBUFCAP) lbuf[p] = (tok << 13) | (unsigned)code;
        }
      }
    }
  }

  __syncthreads();
  unsigned m = lcnt > LBUFCAP ? LBUFCAP : lcnt;
  if (threadIdx.x == 0) gbase = atomicAdd(cnt, m);
  __syncthreads();
  for (unsigned i = threadIdx.x; i < m; i += 256) {
    unsigned p = gbase + i;
    if (p < LISTCAP) list[p] = lbuf[i];
  }
}

// ---- exact fp32 refinement; (score,code) packed u64 atomicMin ----
__global__ __launch_bounds__(256) void refine_kernel(const unsigned* __restrict__ cnt,
                                                     const unsigned* __restrict__ list,
                                                     const float* __restrict__ x,
                                                     const float* __restrict__ cb,
                                                     const float* __restrict__ c2,
                                                     unsigned long long* __restrict__ best) {
  unsigned n = *cnt; if (n > LISTCAP) n = LISTCAP;
  for (unsigned i = blockIdx.x * 256 + threadIdx.x; i < n; i += gridDim.x * 256) {
    unsigned e = list[i];
    int tok = (int)(e >> 13), code = (int)(e & 8191u);
    const float4* xr = (const float4*)(x + (size_t)tok * DD);
    const float4* cr = (const float4*)(cb + (size_t)code * DD);
    float d = 0.f;
    #pragma unroll
    for (int j = 0; j < DD / 4; ++j) {
      float4 av = xr[j], bv = cr[j];
      d = fmaf(av.x, bv.x, d); d = fmaf(av.y, bv.y, d);
      d = fmaf(av.z, bv.z, d); d = fmaf(av.w, bv.w, d);
    }
    float sc = fmaf(-2.f, d, c2[code]);
    unsigned long long key = ((unsigned long long)ford(sc) << 32) | (unsigned long long)code;
    atomicMin(&best[tok], key);
  }
}

// ---- per-token finalize ----
__global__ __launch_bounds__(256) void tokfin_kernel(const unsigned long long* __restrict__ best,
                                                     const float* __restrict__ x,
                                                     const float* __restrict__ cb,
                                                     float* __restrict__ quant,
                                                     float* __restrict__ counts,
                                                     float* __restrict__ sums) {
  const int n = blockIdx.x * 4 + (threadIdx.x >> 6);   // grid 4096
  const int d = threadIdx.x & 63;
  const unsigned code = (unsigned)(best[n] & 0xFFFFFFFFULL);
  quant[(size_t)n * DD + d] = cb[(size_t)code * DD + d];
  atomicAdd(&sums[(size_t)code * DD + d], x[(size_t)n * DD + d]);
  if (d == 0) atomicAdd(&counts[code], 1.0f);
}

// ---- scatter ones into memset-zeroed one-hot ----
__global__ __launch_bounds__(256) void scatter_kernel(const unsigned long long* __restrict__ best,
                                                      float* __restrict__ disc) {
  const int n = blockIdx.x * 256 + threadIdx.x;        // grid 64
  const unsigned code = (unsigned)(best[n] & 0xFFFFFFFFULL);
  disc[(size_t)n * KK + code] = 1.0f;
}

// ---- EMA finalize ----
__global__ __launch_bounds__(256) void finalize_kernel(
    const float* __restrict__ ema_count, const float* __restrict__ ema_weight,
    const float* __restrict__ counts, const float* __restrict__ sums,
    float* __restrict__ out_count, float* __restrict__ out_weight,
    float* __restrict__ out_cb) {
  const int e4 = blockIdx.x * 256 + threadIdx.x;
  const int k = e4 >> 4;
  float nc = ema_count[k] * DECAYF + counts[k] * (1.f - DECAYF);
  nc = (nc + EPSF) / (BATCHF + (float)KK * EPSF) * BATCHF;
  const float4 ew = ((const float4*)ema_weight)[e4];
  const float4 s  = ((const float4*)sums)[e4];
  float4 nw;
  nw.x = ew.x * DECAYF + s.x * (1.f - DECAYF);
  nw.y = ew.y * DECAYF + s.y * (1.f - DECAYF);
  nw.z = ew.z * DECAYF + s.z * (1.f - DECAYF);
  nw.w = ew.w * DECAYF + s.w * (1.f - DECAYF);
  ((float4*)out_weight)[e4] = nw;
  float4 ncb = make_float4(nw.x / nc, nw.y / nc, nw.z / nc, nw.w / nc);
  ((float4*)out_cb)[e4] = ncb;
  if ((e4 & 15) == 0) out_count[k] = nc;
}

extern "C" void kernel_launch(void* const* d_in, const int* in_sizes, int n_in,
                              void* d_out, int out_size, void* d_ws, size_t ws_size,
                              hipStream_t stream) {
  const float* x  = (const float*)d_in[0];
  const float* cb = (const float*)d_in[1];
  const float* ema_count  = (const float*)d_in[2];
  const float* ema_weight = (const float*)d_in[3];

  float* out        = (float*)d_out;
  float* disc       = out;
  float* quant      = disc + (size_t)NN * KK;
  float* out_count  = quant + (size_t)NN * DD;
  float* out_weight = out_count + KK;
  float* out_cb     = out_weight + (size_t)KK * DD;

  float* ws = (float*)d_ws;
  float*    sums   = ws;
  float*    counts = sums + (size_t)KK * DD;
  float*    c2     = counts + KK;
  unsigned* minc   = (unsigned*)(c2 + KK);
  unsigned long long* best = (unsigned long long*)(minc + NN);
  unsigned* cnt    = (unsigned*)(best + NN);
  unsigned* list   = cnt + 16;
  unsigned short* xb  = (unsigned short*)(list + LISTCAP);
  unsigned short* cbb = xb + (size_t)NN * DD;

  hipMemsetAsync(disc, 0, (size_t)NN * KK * sizeof(float), stream);

  init_kernel<<<520, 256, 0, stream>>>((float4*)sums, minc, best, cnt);
  conv_kernel<<<NN * DD / 4 / 256, 256, 0, stream>>>((const float4*)x, (uint2*)xb, NN * DD / 4);
  conv_kernel<<<KK * DD / 4 / 256, 256, 0, stream>>>((const float4*)cb, (uint2*)cbb, KK * DD / 4);
  c2_kernel<<<KK / 256, 256, 0, stream>>>(cb, c2);
  pass1_kernel<<<(NN / 512) * CSPLIT, 256, 0, stream>>>(xb, (const float4*)cbb, c2, minc);
  pass2_kernel<<<(NN / 512) * CSPLIT, 256, 0, stream>>>(xb, (const float4*)cbb, c2, minc, cnt, list);
  refine_kernel<<<256, 256, 0, stream>>>(cnt, list, x, cb, c2, best);
  tokfin_kernel<<<NN / 4, 256, 0, stream>>>(best, x, cb, quant, counts, sums);
  scatter_kernel<<<NN / 256, 256, 0, stream>>>(best, disc);
  finalize_kernel<<<KK * DD / 4 / 256, 256, 0, stream>>>(
      ema_count, ema_weight, counts, sums, out_count, out_weight, out_cb);
}